// Round 2
// baseline (716.041 us; speedup 1.0000x reference)
//
#include <hip/hip_runtime.h>

// VoxelPooler via bucket sort.
// R5: bucket sort, 622us. R6: 4-pt float4 gather, 600us (pool ~2.0 TB/s).
// R7: channel-slice x x-group pool blocks. Old epilogue wrote 400-B segments
// strided 160 KB (DRAM thrash -> ~2 TB/s writes). New block = (b,z,4 x-rows,
// 16-ch slice): LDS tile [16c][4x][200y], epilogue writes 3.2 KB contiguous
// 128-B-aligned segments, nontemporal. Feature rows split 4-way across
// bid-adjacent sibling blocks; 177 MB feat fits L3 so HBM read traffic ~same.
// R7b: nontemporal store via clang ext_vector float4 (HIP float4 class type
// is rejected by __builtin_nontemporal_store on gfx950).
// geometry [B=4, N=6, D=41, H=16, W=44, 3] f32
// features [B, N, D, H, W, C=64] f32
// out      [B, Z*C=512, X=200, Y=200] f32

#define GRID_X 200
#define GRID_Y 200
#define GRID_Z 8
#define NCH 64
#define NB 4
#define PTS_PER_BATCH (6 * 41 * 16 * 44)   // 173184
#define TOTAL_POINTS (NB * PTS_PER_BATCH)  // 692736
#define OUT_FLOATS ((long long)NB * GRID_Z * NCH * GRID_X * GRID_Y)  // 81,920,000

#define XG 4                       // x rows per block
#define NXG (GRID_X / XG)          // 50
#define CS 16                      // channels per slice
#define NSLICE (NCH / CS)          // 4
#define NBUCK (NB * GRID_Z * NXG)  // 1600 buckets: (b, z, xg)
#define YSTRIDE 201                // odd: LDS atomic scatter 2-way banks (free)
#define ACC_FLOATS (CS * XG * YSTRIDE)  // 12864 floats = 51456 B -> 3 blk/CU

typedef float nt4 __attribute__((ext_vector_type(4)));   // native vec for nt-store

// ws layout (ints):
// cnt[NBUCK] | starts[NBUCK+1] | cursor[NBUCK] | sorted[TOTAL_POINTS] | pcode[TOTAL_POINTS]
#define WS_CNT     0
#define WS_STARTS  (NBUCK)
#define WS_CURSOR  (2 * NBUCK + 1)
#define WS_SORTED  (3 * NBUCK + 1)
#define WS_PCODE   (3 * NBUCK + 1 + TOTAL_POINTS)
#define WS_INTS    (3 * NBUCK + 1 + 2 * TOTAL_POINTS)

__device__ __forceinline__ bool point_voxel(const float* __restrict__ geom,
                                            const float* __restrict__ vsz,
                                            const float* __restrict__ vorg,
                                            int i, int& vx, int& vy, int& vz) {
    float px = geom[(size_t)i * 3 + 0];
    float py = geom[(size_t)i * 3 + 1];
    float pz = geom[(size_t)i * 3 + 2];
    // Exact IEEE divide + floorf to match the numpy reference at bin edges.
    vx = (int)floorf((px - vorg[0]) / vsz[0]);
    vy = (int)floorf((py - vorg[1]) / vsz[1]);
    vz = (int)floorf((pz - vorg[2]) / vsz[2]);
    return (vx >= 0 && vx < GRID_X && vy >= 0 && vy < GRID_Y &&
            vz >= 0 && vz < GRID_Z);
}

__global__ __launch_bounds__(256) void zero_cnt_kernel(int* __restrict__ cnt) {
    int i = blockIdx.x * 256 + threadIdx.x;
    if (i < NBUCK) cnt[i] = 0;
}

// Histogram + cache packed point code so scatter_idx skips the geometry
// re-read. pcode: bit31=valid, bits[20:13]=vy, bits[12:11]=xl, bits[10:0]=bucket.
__global__ __launch_bounds__(256) void hist_kernel(
    const float* __restrict__ geom, const float* __restrict__ vsz,
    const float* __restrict__ vorg, int* __restrict__ cnt,
    unsigned* __restrict__ pcode) {
    int i = blockIdx.x * 256 + threadIdx.x;
    if (i >= TOTAL_POINTS) return;
    int vx, vy, vz;
    unsigned code = 0;
    if (point_voxel(geom, vsz, vorg, i, vx, vy, vz)) {
        int b = i / PTS_PER_BATCH;
        int bucket = (b * GRID_Z + vz) * NXG + (vx >> 2);   // < 1600
        code = 0x80000000u | ((unsigned)vy << 13) |
               ((unsigned)(vx & 3) << 11) | (unsigned)bucket;
        atomicAdd(&cnt[bucket], 1);
    }
    pcode[i] = code;
}

// One block, 256 threads, each owns CHUNK contiguous counters (guarded).
__global__ __launch_bounds__(256) void scan_kernel(
    const int* __restrict__ cnt, int* __restrict__ starts, int* __restrict__ cursor) {
    __shared__ int partial[256];
    int t = threadIdx.x;
    const int CHUNK = (NBUCK + 255) / 256;   // 7
    int base = t * CHUNK;
    int s = 0;
    for (int j = 0; j < CHUNK; ++j) {
        int k = base + j;
        if (k < NBUCK) s += cnt[k];
    }
    partial[t] = s;
    __syncthreads();
    for (int off = 1; off < 256; off <<= 1) {
        int v = (t >= off) ? partial[t - off] : 0;
        __syncthreads();
        partial[t] += v;
        __syncthreads();
    }
    int run = partial[t] - s;   // exclusive prefix of this chunk
    for (int j = 0; j < CHUNK; ++j) {
        int k = base + j;
        if (k < NBUCK) {
            int c = cnt[k];
            starts[k] = run;
            cursor[k] = run;
            run += c;
        }
    }
    if (t == 255) starts[NBUCK] = partial[255];
}

__global__ __launch_bounds__(256) void scatter_idx_kernel(
    const unsigned* __restrict__ pcode, int* __restrict__ cursor,
    unsigned* __restrict__ sorted) {
    int i = blockIdx.x * 256 + threadIdx.x;
    if (i >= TOTAL_POINTS) return;
    unsigned code = pcode[i];
    if (!(code & 0x80000000u)) return;
    int bucket = (int)(code & 0x7FFu);
    unsigned xl = (code >> 11) & 3u;
    unsigned yl = (code >> 13) & 0xFFu;
    int pos = atomicAdd(&cursor[bucket], 1);
    // i < 2^20, xl 2b @ bit20, yl 8b @ bit22
    sorted[pos] = (unsigned)i | (xl << 20) | (yl << 22);
}

// One block per (bucket, channel-slice). bucket = (b*GZ+z)*NXG + xg.
// Gather: 16 points per wave-iteration, 4 lanes x float4 (64 B slice) each.
// Accumulate acc[c_local][xl][y] in LDS (YSTRIDE=201 keeps atomics ~2-way),
// then write 16 contiguous 3.2 KB 128-B-aligned segments, nontemporal.
__global__ __launch_bounds__(256) void pool_kernel(
    const float4* __restrict__ feat4, const unsigned* __restrict__ sorted,
    const int* __restrict__ starts, float* __restrict__ out) {
    __shared__ __align__(16) float acc[ACC_FLOATS];   // 51456 B
    int t = threadIdx.x;
    int bid = blockIdx.x;
    int cs = bid & (NSLICE - 1);   // channel slice 0..3
    int bucket = bid >> 2;         // 0..1599 (siblings bid-adjacent: L2/L3 reuse)

    float4* a4 = (float4*)acc;
    for (int i = t; i < ACC_FLOATS / 4; i += 256)
        a4[i] = make_float4(0.f, 0.f, 0.f, 0.f);
    __syncthreads();

    int s0 = starts[bucket];
    int s1 = starts[bucket + 1];
    int w = t >> 6;            // wave 0..3
    int g = (t >> 2) & 15;     // point slot within wave (16 pts/wave-iter)
    int l = t & 3;             // float4 slot: local channels 4l..4l+3

    for (int p0 = s0 + w * 16; p0 < s1; p0 += 64) {
        int p = p0 + g;
        if (p < s1) {
            unsigned pk = sorted[p];
            unsigned idx = pk & 0xFFFFFu;
            int xl = (int)((pk >> 20) & 3u);
            int yl = (int)(pk >> 22);
            float4 f = feat4[(size_t)idx * (NCH / 4) + cs * (CS / 4) + l];
            int cb = 4 * l;
            atomicAdd(&acc[((cb + 0) * XG + xl) * YSTRIDE + yl], f.x);
            atomicAdd(&acc[((cb + 1) * XG + xl) * YSTRIDE + yl], f.y);
            atomicAdd(&acc[((cb + 2) * XG + xl) * YSTRIDE + yl], f.z);
            atomicAdd(&acc[((cb + 3) * XG + xl) * YSTRIDE + yl], f.w);
        }
    }
    __syncthreads();

    int xg = bucket % NXG;
    int bz = bucket / NXG;     // b*GRID_Z + z
    int x0 = xg * XG;

    // 16 c_local x 4 xl x 50 j = 3200 float4 stores; per (c_local): 4 x-rows
    // x 800 B = 3.2 KB contiguous, 128-B aligned (800*XG % 128 == 0).
    nt4* out4 = (nt4*)out;
    for (int i = t; i < CS * XG * (GRID_Y / 4); i += 256) {
        int j = i % (GRID_Y / 4);
        int cx = i / (GRID_Y / 4);       // c_local*XG + xl
        int y0 = 4 * j;
        nt4 v = {acc[cx * YSTRIDE + y0 + 0],
                 acc[cx * YSTRIDE + y0 + 1],
                 acc[cx * YSTRIDE + y0 + 2],
                 acc[cx * YSTRIDE + y0 + 3]};
        int xl = cx & 3;
        int cl = cx >> 2;
        int cc = cs * CS + cl;
        size_t o4 = (((size_t)bz * NCH + cc) * GRID_X + (x0 + xl)) * (GRID_Y / 4) + j;
        __builtin_nontemporal_store(v, &out4[o4]);
    }
}

// ---------- fallback path (R4): atomic scatter ----------
__global__ __launch_bounds__(256) void zero_out_kernel(float4* __restrict__ out) {
    const long long n4 = OUT_FLOATS / 4;
    long long stride = (long long)gridDim.x * blockDim.x;
    for (long long i = blockIdx.x * (long long)blockDim.x + threadIdx.x;
         i < n4; i += stride)
        out[i] = make_float4(0.f, 0.f, 0.f, 0.f);
}

__global__ __launch_bounds__(256) void voxel_scatter_kernel(
    const float* __restrict__ geom, const float* __restrict__ feat,
    const float* __restrict__ vsz, const float* __restrict__ vorg,
    float* __restrict__ out) {
    int gid = blockIdx.x * blockDim.x + threadIdx.x;
    int pt = gid >> 6;
    int c = gid & 63;
    if (pt >= TOTAL_POINTS) return;
    int vx, vy, vz;
    if (!point_voxel(geom, vsz, vorg, pt, vx, vy, vz)) return;
    int b = pt / PTS_PER_BATCH;
    float f = feat[(size_t)pt * NCH + c];
    size_t idx = ((((size_t)b * GRID_Z + vz) * NCH + c) * GRID_X + vx) * GRID_Y + vy;
    atomicAdd(out + idx, f);
}

extern "C" void kernel_launch(void* const* d_in, const int* in_sizes, int n_in,
                              void* d_out, int out_size, void* d_ws, size_t ws_size,
                              hipStream_t stream) {
    const float* geom = (const float*)d_in[0];
    const float* feat = (const float*)d_in[1];
    const float* vsz  = (const float*)d_in[2];
    const float* vorg = (const float*)d_in[3];
    float* out = (float*)d_out;

    if (ws_size >= (size_t)WS_INTS * sizeof(int)) {
        int* ws = (int*)d_ws;
        int* cnt = ws + WS_CNT;
        int* starts = ws + WS_STARTS;
        int* cursor = ws + WS_CURSOR;
        unsigned* sorted = (unsigned*)(ws + WS_SORTED);
        unsigned* pcode  = (unsigned*)(ws + WS_PCODE);

        zero_cnt_kernel<<<(NBUCK + 255) / 256, 256, 0, stream>>>(cnt);
        hist_kernel<<<TOTAL_POINTS / 256, 256, 0, stream>>>(geom, vsz, vorg, cnt, pcode);
        scan_kernel<<<1, 256, 0, stream>>>(cnt, starts, cursor);
        scatter_idx_kernel<<<TOTAL_POINTS / 256, 256, 0, stream>>>(pcode, cursor, sorted);
        pool_kernel<<<NBUCK * NSLICE, 256, 0, stream>>>(
            (const float4*)feat, sorted, starts, out);
    } else {
        // ws too small: R4 atomic-scatter fallback
        zero_out_kernel<<<2048, 256, 0, stream>>>((float4*)out);
        const long long total_threads = (long long)TOTAL_POINTS * NCH;
        voxel_scatter_kernel<<<(int)((total_threads + 255) / 256), 256, 0, stream>>>(
            geom, feat, vsz, vorg, out);
    }
}

// Round 3
// 626.122 us; speedup vs baseline: 1.1436x; 1.1436x over previous
//
#include <hip/hip_runtime.h>

// VoxelPooler via bucket sort.
// R5: bucket sort, 622us. R6: 4-pt float4 gather (256-B rows), 600us.
// R7: channel-sliced gather (64-B slices) + NT stores: 716us REGRESSION —
//     4x random-read transaction count outweighed the 3.2KB write granule.
// R8: revert to R6 full-row gather; merge yt halves: bucket=(b,z,x) (6400),
//     LDS [200y][65] = 52KB (3 blk/CU), epilogue 800-B segments (2x R6
//     granule, half the segments). Keep NT stores (write-once output must
//     not evict the 177MB feature set from L3).
// geometry [B=4, N=6, D=41, H=16, W=44, 3] f32
// features [B, N, D, H, W, C=64] f32
// out      [B, Z*C=512, X=200, Y=200] f32

#define GRID_X 200
#define GRID_Y 200
#define GRID_Z 8
#define NCH 64
#define NB 4
#define PTS_PER_BATCH (6 * 41 * 16 * 44)   // 173184
#define TOTAL_POINTS (NB * PTS_PER_BATCH)  // 692736
#define OUT_FLOATS ((long long)NB * GRID_Z * NCH * GRID_X * GRID_Y)  // 81,920,000

#define NBUCK (NB * GRID_Z * GRID_X)   // 6400 buckets: (b, z, x)
#define LDS_STRIDE 65                  // acc[y][c] padded: 2-way banks (free)
#define ACC_FLOATS (GRID_Y * LDS_STRIDE)   // 13000 floats = 52000 B -> 3 blk/CU

typedef float nt4 __attribute__((ext_vector_type(4)));   // native vec for nt-store

// ws layout (ints):
// cnt[NBUCK] | starts[NBUCK+1] | cursor[NBUCK] | sorted[TOTAL_POINTS] | pcode[TOTAL_POINTS]
#define WS_CNT     0
#define WS_STARTS  (NBUCK)
#define WS_CURSOR  (2 * NBUCK + 1)
#define WS_SORTED  (3 * NBUCK + 1)
#define WS_PCODE   (3 * NBUCK + 1 + TOTAL_POINTS)
#define WS_INTS    (3 * NBUCK + 1 + 2 * TOTAL_POINTS)

__device__ __forceinline__ bool point_voxel(const float* __restrict__ geom,
                                            const float* __restrict__ vsz,
                                            const float* __restrict__ vorg,
                                            int i, int& vx, int& vy, int& vz) {
    float px = geom[(size_t)i * 3 + 0];
    float py = geom[(size_t)i * 3 + 1];
    float pz = geom[(size_t)i * 3 + 2];
    // Exact IEEE divide + floorf to match the numpy reference at bin edges.
    vx = (int)floorf((px - vorg[0]) / vsz[0]);
    vy = (int)floorf((py - vorg[1]) / vsz[1]);
    vz = (int)floorf((pz - vorg[2]) / vsz[2]);
    return (vx >= 0 && vx < GRID_X && vy >= 0 && vy < GRID_Y &&
            vz >= 0 && vz < GRID_Z);
}

__global__ __launch_bounds__(256) void zero_cnt_kernel(int* __restrict__ cnt) {
    int i = blockIdx.x * 256 + threadIdx.x;
    if (i < NBUCK) cnt[i] = 0;
}

// Histogram + cache packed point code so scatter_idx skips the geometry
// re-read. pcode: bit31=valid, bits[20:13]=vy, bits[12:0]=bucket (<6400).
__global__ __launch_bounds__(256) void hist_kernel(
    const float* __restrict__ geom, const float* __restrict__ vsz,
    const float* __restrict__ vorg, int* __restrict__ cnt,
    unsigned* __restrict__ pcode) {
    int i = blockIdx.x * 256 + threadIdx.x;
    if (i >= TOTAL_POINTS) return;
    int vx, vy, vz;
    unsigned code = 0;
    if (point_voxel(geom, vsz, vorg, i, vx, vy, vz)) {
        int b = i / PTS_PER_BATCH;
        int bucket = (b * GRID_Z + vz) * GRID_X + vx;   // < 6400
        code = 0x80000000u | ((unsigned)vy << 13) | (unsigned)bucket;
        atomicAdd(&cnt[bucket], 1);
    }
    pcode[i] = code;
}

// One block, 256 threads, each owns 25 contiguous counters.
__global__ __launch_bounds__(256) void scan_kernel(
    const int* __restrict__ cnt, int* __restrict__ starts, int* __restrict__ cursor) {
    __shared__ int partial[256];
    int t = threadIdx.x;
    const int CHUNK = NBUCK / 256;   // 25
    int base = t * CHUNK;
    int s = 0;
    for (int j = 0; j < CHUNK; ++j) s += cnt[base + j];
    partial[t] = s;
    __syncthreads();
    for (int off = 1; off < 256; off <<= 1) {
        int v = (t >= off) ? partial[t - off] : 0;
        __syncthreads();
        partial[t] += v;
        __syncthreads();
    }
    int run = partial[t] - s;   // exclusive prefix of this chunk
    for (int j = 0; j < CHUNK; ++j) {
        int c = cnt[base + j];
        starts[base + j] = run;
        cursor[base + j] = run;
        run += c;
    }
    if (t == 255) starts[NBUCK] = partial[255];
}

__global__ __launch_bounds__(256) void scatter_idx_kernel(
    const unsigned* __restrict__ pcode, int* __restrict__ cursor,
    unsigned* __restrict__ sorted) {
    int i = blockIdx.x * 256 + threadIdx.x;
    if (i >= TOTAL_POINTS) return;
    unsigned code = pcode[i];
    if (!(code & 0x80000000u)) return;
    int bucket = (int)(code & 0x1FFFu);
    unsigned yl = (code >> 13) & 0xFFu;
    int pos = atomicAdd(&cursor[bucket], 1);
    sorted[pos] = (unsigned)i | (yl << 20);   // i < 2^20, yl < 256
}

// One block per bucket (b, z, x). Gather: 4 points per wave-iteration,
// 16 lanes x float4 each (full 256-B feature row per point -> max MLP).
// Accumulate acc[y][c] in LDS, then write 64 channel-segments of 800 B
// contiguous each (2x the R6 granule), nontemporal (keep output out of L3).
__global__ __launch_bounds__(256) void pool_kernel(
    const float4* __restrict__ feat4, const unsigned* __restrict__ sorted,
    const int* __restrict__ starts, float* __restrict__ out) {
    __shared__ __align__(16) float acc[ACC_FLOATS];   // 52000 B
    int t = threadIdx.x;
    int bid = blockIdx.x;

    // zero LDS with float4 stores: 13000 floats = 3250 float4
    float4* a4 = (float4*)acc;
    for (int i = t; i < ACC_FLOATS / 4; i += 256)
        a4[i] = make_float4(0.f, 0.f, 0.f, 0.f);
    __syncthreads();

    int s0 = starts[bid];
    int s1 = starts[bid + 1];
    int w = t >> 6;            // wave 0..3
    int g = (t >> 4) & 3;      // point slot within wave (4 pts/wave-iter)
    int l = t & 15;            // float4 slot: channels 4l..4l+3

    for (int p0 = s0 + w * 4; p0 < s1; p0 += 16) {
        int p = p0 + g;
        if (p < s1) {
            unsigned pk = sorted[p];
            unsigned idx = pk & 0xFFFFFu;
            unsigned yl = pk >> 20;
            float4 f = feat4[(size_t)idx * 16 + l];
            float* row = &acc[yl * LDS_STRIDE + 4 * l];
            atomicAdd(row + 0, f.x);
            atomicAdd(row + 1, f.y);
            atomicAdd(row + 2, f.z);
            atomicAdd(row + 3, f.w);
        }
    }
    __syncthreads();

    // bid = (b*GZ+z)*GX + x
    int x = bid % GRID_X;
    int bz = bid / GRID_X;     // b*GRID_Z + z

    // 64 channels x 50 float4 (=200 y) = 3200 float4 stores; per channel:
    // 800 B contiguous at stride 160 KB.
    nt4* out4 = (nt4*)out;
    for (int i = t; i < NCH * (GRID_Y / 4); i += 256) {
        int cc = i / (GRID_Y / 4);
        int j = i % (GRID_Y / 4);
        int y0 = 4 * j;
        nt4 v = {acc[(y0 + 0) * LDS_STRIDE + cc],
                 acc[(y0 + 1) * LDS_STRIDE + cc],
                 acc[(y0 + 2) * LDS_STRIDE + cc],
                 acc[(y0 + 3) * LDS_STRIDE + cc]};
        size_t o4 = (((size_t)bz * NCH + cc) * GRID_X + x) * (GRID_Y / 4) + j;
        __builtin_nontemporal_store(v, &out4[o4]);
    }
}

// ---------- fallback path (R4): atomic scatter ----------
__global__ __launch_bounds__(256) void zero_out_kernel(float4* __restrict__ out) {
    const long long n4 = OUT_FLOATS / 4;
    long long stride = (long long)gridDim.x * blockDim.x;
    for (long long i = blockIdx.x * (long long)blockDim.x + threadIdx.x;
         i < n4; i += stride)
        out[i] = make_float4(0.f, 0.f, 0.f, 0.f);
}

__global__ __launch_bounds__(256) void voxel_scatter_kernel(
    const float* __restrict__ geom, const float* __restrict__ feat,
    const float* __restrict__ vsz, const float* __restrict__ vorg,
    float* __restrict__ out) {
    int gid = blockIdx.x * blockDim.x + threadIdx.x;
    int pt = gid >> 6;
    int c = gid & 63;
    if (pt >= TOTAL_POINTS) return;
    int vx, vy, vz;
    if (!point_voxel(geom, vsz, vorg, pt, vx, vy, vz)) return;
    int b = pt / PTS_PER_BATCH;
    float f = feat[(size_t)pt * NCH + c];
    size_t idx = ((((size_t)b * GRID_Z + vz) * NCH + c) * GRID_X + vx) * GRID_Y + vy;
    atomicAdd(out + idx, f);
}

extern "C" void kernel_launch(void* const* d_in, const int* in_sizes, int n_in,
                              void* d_out, int out_size, void* d_ws, size_t ws_size,
                              hipStream_t stream) {
    const float* geom = (const float*)d_in[0];
    const float* feat = (const float*)d_in[1];
    const float* vsz  = (const float*)d_in[2];
    const float* vorg = (const float*)d_in[3];
    float* out = (float*)d_out;

    if (ws_size >= (size_t)WS_INTS * sizeof(int)) {
        int* ws = (int*)d_ws;
        int* cnt = ws + WS_CNT;
        int* starts = ws + WS_STARTS;
        int* cursor = ws + WS_CURSOR;
        unsigned* sorted = (unsigned*)(ws + WS_SORTED);
        unsigned* pcode  = (unsigned*)(ws + WS_PCODE);

        zero_cnt_kernel<<<(NBUCK + 255) / 256, 256, 0, stream>>>(cnt);
        hist_kernel<<<TOTAL_POINTS / 256, 256, 0, stream>>>(geom, vsz, vorg, cnt, pcode);
        scan_kernel<<<1, 256, 0, stream>>>(cnt, starts, cursor);
        scatter_idx_kernel<<<TOTAL_POINTS / 256, 256, 0, stream>>>(pcode, cursor, sorted);
        pool_kernel<<<NBUCK, 256, 0, stream>>>(
            (const float4*)feat, sorted, starts, out);
    } else {
        // ws too small: R4 atomic-scatter fallback
        zero_out_kernel<<<2048, 256, 0, stream>>>((float4*)out);
        const long long total_threads = (long long)TOTAL_POINTS * NCH;
        voxel_scatter_kernel<<<(int)((total_threads + 255) / 256), 256, 0, stream>>>(
            geom, feat, vsz, vorg, out);
    }
}